// Round 5
// baseline (500.570 us; speedup 1.0000x reference)
//
#include <hip/hip_runtime.h>

// SimpleCA: fused toroidal depthwise 3x3 stencil + 1x1 MLP (4->6 relu ->4) + masked residual.
// NHWC, C=4 -> one float4 per pixel.
//
// R4 post-mortem: rolling-window (R=8) kernel is latency-bound at 2.9 TB/s:
// ~0.27 outstanding loads/wave (BW*latency / resident waves). The serial
// 8-iteration chain drains the load queue every row. R=16 (190us) > R=8
// (162us) -> less serial work per thread is better.
//
// R5: R=1 -- the memcpy shape. One pixel per thread, 16M threads:
//  - 9 independent ld4 + 1 rnd load issued up-front, no dependent chain,
//    ~75 VALU, one store, exit. MLP per wave: ~9KB in flight vs ~0.27KB.
//  - 3x row re-read is served by L1 (same-wave overlap), L2/L3 (adjacent-row
//    blocks are schedule-adjacent; XCD-chunked swizzle keeps an image's rows
//    on one XCD's L2). L2 demand ~24 TB/s < 34.5 TB/s ceiling.
//  - Weights: wave-uniform -> s_load/SGPR (SGPR_Count 80 in prior rounds).
//  - Normal stores (NT regressed in R2); no launch_bounds min-wave clamp (R3 spill).

constexpr int H = 512, W = 512, C = 4, HIDN = 6;
constexpr int NXCD = 8;

typedef float f32x4 __attribute__((ext_vector_type(4)));

__device__ __forceinline__ f32x4 ld4(const float* p) {
    return *reinterpret_cast<const f32x4*>(p);
}

__global__ __launch_bounds__(256) void ca_kernel(
    const float* __restrict__ x,
    const float* __restrict__ rnd,
    const float* __restrict__ w1,
    const float* __restrict__ b1,
    const float* __restrict__ w2,
    float* __restrict__ out)
{
    // Chunked XCD swizzle (65536 blocks % 8 == 0 -> bijective). Keeps the
    // rows of one image-region resident on a single XCD's L2 so the 3x
    // vertical re-read hits L2, not HBM.
    const int nblk  = (int)gridDim.x;
    const int chunk = nblk / NXCD;
    const int bid   = (int)blockIdx.x;
    const int swz   = (bid & (NXCD - 1)) * chunk + (bid >> 3);

    const int t = swz * (int)blockDim.x + (int)threadIdx.x;   // [0, 16M)
    const int w = t & (W - 1);                 // lane-fast -> coalesced
    const int h = (t >> 9) & (H - 1);
    const int b = t >> 18;                     // H*W = 2^18

    const int wm = (w == 0) ? (W - 1) : (w - 1);
    const int wp = (w == W - 1) ? 0 : (w + 1);
    const int hm = (h == 0) ? (H - 1) : (h - 1);
    const int hp = (h == H - 1) ? 0 : (h + 1);
    const int om = wm << 2, oc = w << 2, op = wp << 2;

    const float* xb = x + (size_t)b * (H * W * C);
    const float* rA = xb + (size_t)hm * (W * C);
    const float* rC = xb + (size_t)h  * (W * C);
    const float* rD = xb + (size_t)hp * (W * C);

    // Issue all 10 vector loads up-front; fully independent.
    const f32x4 a0 = ld4(rA + om), a1 = ld4(rA + oc), a2 = ld4(rA + op);
    const f32x4 c0 = ld4(rC + om), c1 = ld4(rC + oc), c2 = ld4(rC + op);
    const f32x4 d0 = ld4(rD + om), d1 = ld4(rD + oc), d2 = ld4(rD + op);
    const float rv = rnd[(size_t)b * (H * W) + h * W + w];

    // Weights: uniform -> scalar loads, separate pipe, K$-cached.
    float w1r[C * HIDN], b1r[HIDN], w2r[HIDN * C];
    #pragma unroll
    for (int i = 0; i < C * HIDN; ++i) w1r[i] = w1[i];
    #pragma unroll
    for (int i = 0; i < HIDN; ++i) b1r[i] = b1[i];
    #pragma unroll
    for (int i = 0; i < HIDN * C; ++i) w2r[i] = w2[i];

    // Depthwise stencils (cross-correlation, no flip -- XLA conv semantics).
    const float p0 = c1.x;                                            // identity
    const float p1 = (a2.y - a0.y) + 2.f * (c2.y - c0.y)              // sobel_x
                   + (d2.y - d0.y);
    const float p2 = (d0.z - a0.z) + 2.f * (d1.z - a1.z)              // sobel_y
                   + (d2.z - a2.z);
    const float p3 = a0.w + 2.f * a1.w + a2.w                         // laplacian
                   + 2.f * c0.w - 12.f * c1.w + 2.f * c2.w
                   + d0.w + 2.f * d1.w + d2.w;

    float hid[HIDN];
    #pragma unroll
    for (int j = 0; j < HIDN; ++j) {
        float v = p0 * w1r[j] + p1 * w1r[HIDN + j] + p2 * w1r[2 * HIDN + j]
                + p3 * w1r[3 * HIDN + j] + b1r[j];
        hid[j] = v > 0.f ? v : 0.f;
    }
    float dx0 = 0.f, dx1 = 0.f, dx2 = 0.f, dx3 = 0.f;
    #pragma unroll
    for (int j = 0; j < HIDN; ++j) {
        dx0 += hid[j] * w2r[j * 4 + 0];
        dx1 += hid[j] * w2r[j * 4 + 1];
        dx2 += hid[j] * w2r[j * 4 + 2];
        dx3 += hid[j] * w2r[j * 4 + 3];
    }

    const float mask = floorf(rv + 0.5f);   // exact ref semantics

    f32x4 o;
    o.x = c1.x + dx0 * mask;
    o.y = c1.y + dx1 * mask;
    o.z = c1.z + dx2 * mask;
    o.w = c1.w + dx3 * mask;
    *reinterpret_cast<f32x4*>(out + (size_t)b * (H * W * C) + ((h * W + w) << 2)) = o;
}

extern "C" void kernel_launch(void* const* d_in, const int* in_sizes, int n_in,
                              void* d_out, int out_size, void* d_ws, size_t ws_size,
                              hipStream_t stream) {
    const float* x   = (const float*)d_in[0];
    const float* rnd = (const float*)d_in[1];
    const float* w1  = (const float*)d_in[2];
    const float* b1  = (const float*)d_in[3];
    const float* w2  = (const float*)d_in[4];
    float* out = (float*)d_out;

    const int B = in_sizes[0] / (H * W * C);          // 64
    const long long total_threads = (long long)B * H * W;   // 16,777,216
    dim3 grid((unsigned)(total_threads / 256)), block(256); // 65536 blocks, %8==0
    hipLaunchKernelGGL(ca_kernel, grid, block, 0, stream, x, rnd, w1, b1, w2, out);
}